// Round 2
// baseline (52.060 us; speedup 1.0000x reference)
//
#include <hip/hip_runtime.h>
#include <hip/hip_bf16.h>

// Problem constants: B=8, T=128, n=127 neighbors, Q=K=64, H=4, O=H*K=256
#define NB 127

typedef __attribute__((ext_vector_type(8))) short bf16x8;
typedef __attribute__((ext_vector_type(4))) float f32x4;

// ---- workspace layout (f32 elements unless noted) ----
#define QQ_OFF 0                        // f32[1024*256]  qq = q@Wq.T + bias
#define QV_OFF (1024 * 256)             // f32[1024*256]  qv = q@Wv_q.T + bv
#define WKP_BYTE (2 * 1024 * 256 * 4)   // bf16[16384]    Wk packed fragments
#define WVP_BYTE (WKP_BYTE + 32768)     // bf16[16384]    Wv_kv packed fragments
#define WS_NEEDED (size_t)(WVP_BYTE + 32768)

__device__ __forceinline__ short bfs(float f) {
  __hip_bfloat16 h = __float2bfloat16(f);
  return __builtin_bit_cast(short, h);
}
__device__ __forceinline__ unsigned packbf2(float a, float b) {
  unsigned lo = (unsigned short)bfs(a);
  unsigned hi = (unsigned short)bfs(b);
  return lo | (hi << 16);
}

// ================= prep kernel =================
// blocks 0..255: qq/qv for 4 bt each.  block 256: pack Wk.  block 257: pack Wv_kv.
extern "C" __global__ void __launch_bounds__(256)
prep_kernel(const float* __restrict__ q_x, const float* __restrict__ Wq,
            const float* __restrict__ Wv, const float* __restrict__ Wk,
            const float* __restrict__ bv, const float* __restrict__ bias,
            float* __restrict__ ws_f)
{
  const int blk = blockIdx.x;
  const int tid = threadIdx.x;
  if (blk < 256) {
    __shared__ float qx_s[4][64];
    const int bt0 = blk * 4;
    if (tid < 64) ((float4*)&qx_s[0][0])[tid] = ((const float4*)(q_x + bt0 * 64))[tid];
    __syncthreads();
    const int o = tid;
    const float4* wqr = (const float4*)(Wq + o * 64);
    const float4* wvr = (const float4*)(Wv + o * 128 + 64);
    float qq[4] = {0.f, 0.f, 0.f, 0.f};
    float qv[4] = {0.f, 0.f, 0.f, 0.f};
    #pragma unroll
    for (int i = 0; i < 16; ++i) {
      float4 a = wqr[i];
      float4 c = wvr[i];
      #pragma unroll
      for (int b = 0; b < 4; ++b) {
        float4 x = ((const float4*)&qx_s[b][0])[i];
        qq[b] = fmaf(a.x, x.x, fmaf(a.y, x.y, fmaf(a.z, x.z, fmaf(a.w, x.w, qq[b]))));
        qv[b] = fmaf(c.x, x.x, fmaf(c.y, x.y, fmaf(c.z, x.z, fmaf(c.w, x.w, qv[b]))));
      }
    }
    const float bb = bias[o & 63];
    const float bvv = bv[o];
    #pragma unroll
    for (int b = 0; b < 4; ++b) {
      ws_f[QQ_OFF + (bt0 + b) * 256 + o] = qq[b] + bb;
      ws_f[QV_OFF + (bt0 + b) * 256 + o] = qv[b] + bvv;
    }
  } else {
    const bool isK = (blk == 256);
    const float* src = isK ? Wk : Wv;
    const int stride = isK ? 64 : 128;
    short* dst = (short*)((char*)ws_f + (isK ? WKP_BYTE : WVP_BYTE));
    for (int i = tid; i < 16384; i += 256) {
      int j = i & 7, lane = (i >> 3) & 63, kt = (i >> 9) & 1, nt = (i >> 10) & 3, head = i >> 12;
      int o = head * 64 + nt * 16 + (lane & 15);
      int k = (lane >> 4) * 8 + kt * 32 + j;
      dst[i] = bfs(src[o * stride + k]);
    }
  }
}

// ================= main kernel =================
// grid 2048: bt = blk & 1023, head-pair hp = blk >> 10 (blocks bt and bt+1024 -> same XCD).
// 4 waves: wave = head_local*2 + half; each wave owns 64 n-rows of one head.
template <int PREP>
__global__ __launch_bounds__(256, 6) void
rnn_attn_kernel(const float* __restrict__ q_x, const float* __restrict__ kv_x,
                const float* __restrict__ Wk, const float* __restrict__ Wq,
                const float* __restrict__ Wv, const float* __restrict__ bv,
                const float* __restrict__ bias, const float* __restrict__ wsc,
                const float* __restrict__ ws_f, float* __restrict__ out)
{
  __shared__ __align__(16) unsigned char Atile[128 * 128];
  __shared__ float sc_s[128][5];   // +1 pad: conflict-free column reads
  __shared__ float ps_s[4][64];
  __shared__ float qx_s[64];       // fallback only
  __shared__ float qqb_s[128];     // fallback only
  __shared__ float qv_s[128];      // fallback only

  const int tid = threadIdx.x;
  const int blk = blockIdx.x;
  const int bt = blk & 1023;
  const int hp = blk >> 10;
  const int lane = tid & 63;
  const int wv = tid >> 6;
  const int l15 = lane & 15;
  const int g = lane >> 4;
  const int head_l = wv >> 1;
  const int half = wv & 1;
  const int head = hp * 2 + head_l;
  const int obase = head * 64;

  // ---- Phase A: stage kv tile (127x64 f32 -> bf16, XOR-swizzled LDS) ----
  const float* kv = kv_x + (size_t)bt * (NB * 64);
  #pragma unroll
  for (int i = 0; i < 8; ++i) {
    int idx = i * 256 + tid;
    int row = idx >> 4;
    int c = idx & 15;
    float4 v = (row < NB) ? ((const float4*)kv)[idx] : make_float4(0.f, 0.f, 0.f, 0.f);
    int byte = (row << 7) + (c << 3);
    byte ^= ((row & 7) << 4);
    *(uint2*)(&Atile[byte]) = make_uint2(packbf2(v.x, v.y), packbf2(v.z, v.w));
  }
  if (!PREP && tid < 16) ((float4*)qx_s)[tid] = ((const float4*)(q_x + bt * 64))[tid];

  bf16x8 bfr[4][2];
  float wsv[4], qqv[4];
  if (PREP) {
    // coalesced prepacked fragment loads; overlap with staging latency
    const bf16x8* wkp = (const bf16x8*)((const char*)ws_f + WKP_BYTE);
    #pragma unroll
    for (int nt = 0; nt < 4; ++nt) {
      #pragma unroll
      for (int kt = 0; kt < 2; ++kt)
        bfr[nt][kt] = wkp[((head * 4 + nt) * 2 + kt) * 64 + lane];
      wsv[nt] = wsc[nt * 16 + l15];
      qqv[nt] = ws_f[QQ_OFF + bt * 256 + obase + nt * 16 + l15];
    }
  }
  __syncthreads();

  if (!PREP) {
    if (tid < 128) {
      const int o = hp * 128 + tid;
      float qq = 0.f, qvv = bv[o];
      const float4* wqr = (const float4*)(Wq + o * 64);
      const float4* wvr = (const float4*)(Wv + o * 128 + 64);
      const float4* qx4 = (const float4*)qx_s;
      #pragma unroll
      for (int i = 0; i < 16; ++i) {
        float4 a = wqr[i], x = qx4[i], b = wvr[i];
        qq  = fmaf(a.x, x.x, fmaf(a.y, x.y, fmaf(a.z, x.z, fmaf(a.w, x.w, qq))));
        qvv = fmaf(b.x, x.x, fmaf(b.y, x.y, fmaf(b.z, x.z, fmaf(b.w, x.w, qvv))));
      }
      qqb_s[tid] = qq + bias[o & 63];
      qv_s[tid] = qvv;
    }
    __syncthreads();
    #pragma unroll
    for (int nt = 0; nt < 4; ++nt) {
      const int o = obase + nt * 16 + l15;
      const float* wr = Wk + o * 64 + g * 8;
      #pragma unroll
      for (int kt = 0; kt < 2; ++kt) {
        float4 a = *(const float4*)(wr + kt * 32);
        float4 b = *(const float4*)(wr + kt * 32 + 4);
        bf16x8 f;
        f[0] = bfs(a.x); f[1] = bfs(a.y); f[2] = bfs(a.z); f[3] = bfs(a.w);
        f[4] = bfs(b.x); f[5] = bfs(b.y); f[6] = bfs(b.z); f[7] = bfs(b.w);
        bfr[nt][kt] = f;
      }
      wsv[nt] = wsc[nt * 16 + l15];
      qqv[nt] = qqb_s[head_l * 64 + nt * 16 + l15];
    }
  }

  // ---- Phase C: score GEMM + tanh-score for this wave's 64 rows ----
  #pragma unroll
  for (int mt = 0; mt < 4; ++mt) {
    int row = half * 64 + mt * 16 + l15;
    int byte0 = (row << 7) + g * 16;
    int swz = (row & 7) << 4;
    bf16x8 a0 = *(const bf16x8*)(&Atile[(byte0) ^ swz]);
    bf16x8 a1 = *(const bf16x8*)(&Atile[(byte0 + 64) ^ swz]);
    f32x4 acc[4];
    #pragma unroll
    for (int nt = 0; nt < 4; ++nt) {
      acc[nt] = (f32x4){0.f, 0.f, 0.f, 0.f};
      acc[nt] = __builtin_amdgcn_mfma_f32_16x16x32_bf16(a0, bfr[nt][0], acc[nt], 0, 0, 0);
      acc[nt] = __builtin_amdgcn_mfma_f32_16x16x32_bf16(a1, bfr[nt][1], acc[nt], 0, 0, 0);
    }
    #pragma unroll
    for (int r = 0; r < 4; ++r) {
      float s = 0.f;
      #pragma unroll
      for (int nt = 0; nt < 4; ++nt) {
        float xg = acc[nt][r] + qqv[nt];
        float e = __expf(2.f * xg);                    // tanh(x) = 1 - 2/(e^(2x)+1)
        float th = 1.f - 2.f * __builtin_amdgcn_rcpf(e + 1.f);
        s = fmaf(wsv[nt], th, s);
      }
      s += __shfl_xor(s, 1);
      s += __shfl_xor(s, 2);
      s += __shfl_xor(s, 4);
      s += __shfl_xor(s, 8);
      if (l15 == 0) sc_s[half * 64 + mt * 16 + g * 4 + r][head] = s;
    }
  }
  __syncthreads();

  // ---- Phase D: softmax over n=127 (each wave reduces full column, keeps its half) ----
  float w_loc;
  {
    float s1 = sc_s[lane][head];
    float s2 = (lane < 63) ? sc_s[64 + lane][head] : -1e30f;
    float m = fmaxf(s1, s2);
    #pragma unroll
    for (int d = 1; d < 64; d <<= 1) m = fmaxf(m, __shfl_xor(m, d));
    float e1 = __expf(s1 - m);
    float e2 = (lane < 63) ? __expf(s2 - m) : 0.f;
    float sum = e1 + e2;
    #pragma unroll
    for (int d = 1; d < 64; d <<= 1) sum += __shfl_xor(sum, d);
    float inv = __builtin_amdgcn_rcpf(sum);
    w_loc = (half ? e2 : e1) * inv;   // weight for row half*64 + lane
  }

  // ---- Phase E: value GEMM (kv part) + weighted reduce over this wave's rows ----
  if (PREP) {
    const bf16x8* wvp = (const bf16x8*)((const char*)ws_f + WVP_BYTE);
    #pragma unroll
    for (int nt = 0; nt < 4; ++nt)
      #pragma unroll
      for (int kt = 0; kt < 2; ++kt)
        bfr[nt][kt] = wvp[((head * 4 + nt) * 2 + kt) * 64 + lane];
  } else {
    #pragma unroll
    for (int nt = 0; nt < 4; ++nt) {
      const int o = obase + nt * 16 + l15;
      const float* wr = Wv + o * 128 + g * 8;   // kv part = cols 0..63
      #pragma unroll
      for (int kt = 0; kt < 2; ++kt) {
        float4 a = *(const float4*)(wr + kt * 32);
        float4 b = *(const float4*)(wr + kt * 32 + 4);
        bf16x8 f;
        f[0] = bfs(a.x); f[1] = bfs(a.y); f[2] = bfs(a.z); f[3] = bfs(a.w);
        f[4] = bfs(b.x); f[5] = bfs(b.y); f[6] = bfs(b.z); f[7] = bfs(b.w);
        bfr[nt][kt] = f;
      }
    }
  }

  float cs[4] = {0.f, 0.f, 0.f, 0.f};
  #pragma unroll
  for (int mt = 0; mt < 4; ++mt) {
    int row = half * 64 + mt * 16 + l15;
    int byte0 = (row << 7) + g * 16;
    int swz = (row & 7) << 4;
    bf16x8 a0 = *(const bf16x8*)(&Atile[(byte0) ^ swz]);
    bf16x8 a1 = *(const bf16x8*)(&Atile[(byte0 + 64) ^ swz]);
    f32x4 vac[4];
    #pragma unroll
    for (int nt = 0; nt < 4; ++nt) {
      vac[nt] = (f32x4){0.f, 0.f, 0.f, 0.f};
      vac[nt] = __builtin_amdgcn_mfma_f32_16x16x32_bf16(a0, bfr[nt][0], vac[nt], 0, 0, 0);
      vac[nt] = __builtin_amdgcn_mfma_f32_16x16x32_bf16(a1, bfr[nt][1], vac[nt], 0, 0, 0);
    }
    #pragma unroll
    for (int r = 0; r < 4; ++r) {
      float wgt = __shfl(w_loc, mt * 16 + g * 4 + r);   // weight held by that local row's lane
      #pragma unroll
      for (int nt = 0; nt < 4; ++nt)
        cs[nt] = fmaf(vac[nt][r], wgt, cs[nt]);
    }
  }
  #pragma unroll
  for (int nt = 0; nt < 4; ++nt) {
    cs[nt] += __shfl_xor(cs[nt], 16);
    cs[nt] += __shfl_xor(cs[nt], 32);
  }
  if (g == 0) {
    #pragma unroll
    for (int nt = 0; nt < 4; ++nt) ps_s[wv][nt * 16 + l15] = cs[nt];
  }
  __syncthreads();

  if (tid < 128) {
    const int hl = tid >> 6, idx = tid & 63;
    const int o = (hp * 2 + hl) * 64 + idx;
    float qv = PREP ? ws_f[QV_OFF + bt * 256 + o] : qv_s[tid];
    out[bt * 256 + o] = ps_s[hl * 2][idx] + ps_s[hl * 2 + 1][idx] + qv;
  }
}

extern "C" void kernel_launch(void* const* d_in, const int* in_sizes, int n_in,
                              void* d_out, int out_size, void* d_ws, size_t ws_size,
                              hipStream_t stream) {
  const float* q_x  = (const float*)d_in[0];
  const float* kv_x = (const float*)d_in[1];
  const float* Wk   = (const float*)d_in[2];
  const float* Wq   = (const float*)d_in[3];
  const float* Wv   = (const float*)d_in[4];
  const float* bv   = (const float*)d_in[5];
  const float* bias = (const float*)d_in[6];
  const float* wsc  = (const float*)d_in[7];
  // d_in[8] = bs: constant across neighbors -> cancels in softmax, unused.
  float* out = (float*)d_out;
  float* ws_f = (float*)d_ws;

  if (ws_size >= WS_NEEDED) {
    prep_kernel<<<258, 256, 0, stream>>>(q_x, Wq, Wv, Wk, bv, bias, ws_f);
    rnn_attn_kernel<1><<<2048, 256, 0, stream>>>(q_x, kv_x, Wk, Wq, Wv, bv, bias, wsc, ws_f, out);
  } else {
    rnn_attn_kernel<0><<<2048, 256, 0, stream>>>(q_x, kv_x, Wk, Wq, Wv, bv, bias, wsc, ws_f, out);
  }
}

// Round 3
// 35.809 us; speedup vs baseline: 1.4538x; 1.4538x over previous
//
#include <hip/hip_runtime.h>
#include <hip/hip_bf16.h>

// Problem constants: B=8, T=128, n=127 neighbors, Q=K=64, H=4, O=H*K=256
#define NB 127

typedef __attribute__((ext_vector_type(8))) short bf16x8;
typedef __attribute__((ext_vector_type(4))) float f32x4;

// ---- workspace layout ----
#define QQ_OFF 0                         // f32[1024*256]  qq = q@Wq.T + bias
#define QV_OFF (1024 * 256)              // f32[1024*256]  qv = q@Wv_q.T + bv
#define PACK_BYTE (2 * 1024 * 256 * 4)   // packed bf16 fragments, 4 x 32KB:
#define WKP_S 0                          //   Wk      (shorts offset)
#define WVP_S 16384                      //   Wv_kv
#define WQP_S 32768                      //   Wq
#define WVQP_S 49152                     //   Wv_q
#define WS_NEEDED (size_t)(PACK_BYTE + 4 * 32768)

__device__ __forceinline__ short bfs(float f) {
  __hip_bfloat16 h = __float2bfloat16(f);
  return __builtin_bit_cast(short, h);
}
__device__ __forceinline__ unsigned packbf2(float a, float b) {
  unsigned lo = (unsigned short)bfs(a);
  unsigned hi = (unsigned short)bfs(b);
  return lo | (hi << 16);
}

// ================= prep kernel (grid 48) =================
// blocks 0..31: pack 4 weight matrices into MFMA fragment order (coalesced reads).
// blocks 32..47: qq/qv GEMM via MFMA, 64 bt rows each.
__global__ __launch_bounds__(256, 2) void
prep_kernel(const float* __restrict__ q_x, const float* __restrict__ Wq,
            const float* __restrict__ Wv, const float* __restrict__ Wk,
            const float* __restrict__ bv, const float* __restrict__ bias,
            float* __restrict__ ws_f)
{
  const int blk = blockIdx.x;
  const int tid = threadIdx.x;
  short* dstall = (short*)((char*)ws_f + PACK_BYTE);

  if (blk < 32) {
    // ---- pack: coalesced float4 read, scattered 8B bf16 write ----
    const int m = blk >> 3;      // matrix id
    const int sub = blk & 7;
    const float* src; int stride, off, dsto;
    if (m == 0)      { src = Wk; stride = 64;  off = 0;  dsto = WKP_S; }
    else if (m == 1) { src = Wv; stride = 128; off = 0;  dsto = WVP_S; }
    else if (m == 2) { src = Wq; stride = 64;  off = 0;  dsto = WQP_S; }
    else             { src = Wv; stride = 128; off = 64; dsto = WVQP_S; }
    short* dst = dstall + dsto;
    #pragma unroll
    for (int it = 0; it < 2; ++it) {
      int i4 = sub * 512 + it * 256 + tid;   // float4 index in 256x64 submatrix
      int o = i4 >> 4;
      int c4 = i4 & 15;
      int k0 = c4 * 4;
      float4 v = ((const float4*)(src + o * stride + off))[c4];
      int kt = k0 >> 5, g = (k0 & 31) >> 3, j0 = k0 & 7;
      int head = o >> 6, nt = (o >> 4) & 3, l15 = o & 15;
      int lane = g * 16 + l15;
      int di = (((head * 4 + nt) * 2 + kt) * 64 + lane) * 8 + j0;
      *(uint2*)(dst + di) = make_uint2(packbf2(v.x, v.y), packbf2(v.z, v.w));
    }
  } else {
    // ---- qq/qv GEMM: 64 bt rows, 4 waves (wave = head) ----
    __shared__ __align__(16) unsigned char Qtile[64 * 128];
    const int bt0 = (blk - 32) * 64;
    const int lane = tid & 63;
    const int head = tid >> 6;
    const int l15 = lane & 15;
    const int g = lane >> 4;

    #pragma unroll
    for (int it = 0; it < 4; ++it) {
      int idx = it * 256 + tid;
      int row = idx >> 4, c = idx & 15;
      float4 v = ((const float4*)(q_x + (size_t)(bt0 + row) * 64))[c];
      int byte = (row << 7) + (c << 3);
      byte ^= ((row & 7) << 4);
      *(uint2*)(&Qtile[byte]) = make_uint2(packbf2(v.x, v.y), packbf2(v.z, v.w));
    }

    // B-fragments straight from global (only 16 blocks -> negligible requests)
    bf16x8 bq[4][2], bw[4][2];
    float bias_l[4], bv_l[4];
    #pragma unroll
    for (int nt = 0; nt < 4; ++nt) {
      const int o = head * 64 + nt * 16 + l15;
      const float* wq = Wq + o * 64 + g * 8;
      const float* wv = Wv + o * 128 + 64 + g * 8;
      #pragma unroll
      for (int kt = 0; kt < 2; ++kt) {
        float4 a = *(const float4*)(wq + kt * 32);
        float4 b = *(const float4*)(wq + kt * 32 + 4);
        bf16x8 f;
        f[0] = bfs(a.x); f[1] = bfs(a.y); f[2] = bfs(a.z); f[3] = bfs(a.w);
        f[4] = bfs(b.x); f[5] = bfs(b.y); f[6] = bfs(b.z); f[7] = bfs(b.w);
        bq[nt][kt] = f;
        a = *(const float4*)(wv + kt * 32);
        b = *(const float4*)(wv + kt * 32 + 4);
        f[0] = bfs(a.x); f[1] = bfs(a.y); f[2] = bfs(a.z); f[3] = bfs(a.w);
        f[4] = bfs(b.x); f[5] = bfs(b.y); f[6] = bfs(b.z); f[7] = bfs(b.w);
        bw[nt][kt] = f;
      }
      bias_l[nt] = bias[nt * 16 + l15];
      bv_l[nt] = bv[head * 64 + nt * 16 + l15];
    }
    __syncthreads();

    #pragma unroll
    for (int mt = 0; mt < 4; ++mt) {
      int row = mt * 16 + l15;
      int byte0 = (row << 7) + g * 16;
      int swz = (l15 & 7) << 4;
      bf16x8 a0 = *(const bf16x8*)(&Qtile[(byte0) ^ swz]);
      bf16x8 a1 = *(const bf16x8*)(&Qtile[(byte0 + 64) ^ swz]);
      f32x4 aq[4], av[4];
      #pragma unroll
      for (int nt = 0; nt < 4; ++nt) {
        aq[nt] = (f32x4){0.f, 0.f, 0.f, 0.f};
        aq[nt] = __builtin_amdgcn_mfma_f32_16x16x32_bf16(a0, bq[nt][0], aq[nt], 0, 0, 0);
        aq[nt] = __builtin_amdgcn_mfma_f32_16x16x32_bf16(a1, bq[nt][1], aq[nt], 0, 0, 0);
        av[nt] = (f32x4){0.f, 0.f, 0.f, 0.f};
        av[nt] = __builtin_amdgcn_mfma_f32_16x16x32_bf16(a0, bw[nt][0], av[nt], 0, 0, 0);
        av[nt] = __builtin_amdgcn_mfma_f32_16x16x32_bf16(a1, bw[nt][1], av[nt], 0, 0, 0);
      }
      #pragma unroll
      for (int nt = 0; nt < 4; ++nt) {
        const int o = head * 64 + nt * 16 + l15;
        #pragma unroll
        for (int r = 0; r < 4; ++r) {
          int bt_r = bt0 + mt * 16 + g * 4 + r;
          ws_f[QQ_OFF + bt_r * 256 + o] = aq[nt][r] + bias_l[nt];
          ws_f[QV_OFF + bt_r * 256 + o] = av[nt][r] + bv_l[nt];
        }
      }
    }
  }
}

// ================= main kernel (grid 1024, wave = head) =================
template <int PREP>
__global__ __launch_bounds__(256, 4) void
rnn_attn_kernel(const float* __restrict__ q_x, const float* __restrict__ kv_x,
                const float* __restrict__ Wk, const float* __restrict__ Wq,
                const float* __restrict__ Wv, const float* __restrict__ bv,
                const float* __restrict__ bias, const float* __restrict__ wsc,
                const float* __restrict__ ws_f, float* __restrict__ out)
{
  __shared__ __align__(16) unsigned char Atile[128 * 128];
  __shared__ float sc_s[128][5];
  __shared__ float qx_s[64];     // fallback only
  __shared__ float qqb_s[256];   // fallback only
  __shared__ float qv_s[256];    // fallback only

  const int tid = threadIdx.x;
  const int bt = blockIdx.x;
  const int lane = tid & 63;
  const int head = tid >> 6;
  const int l15 = lane & 15;
  const int g = lane >> 4;
  const int obase = head * 64;

  // ---- stage kv tile (127x64 f32 -> bf16, XOR-swizzled), coalesced ----
  const float* kv = kv_x + (size_t)bt * (NB * 64);
  #pragma unroll
  for (int i = 0; i < 8; ++i) {
    int idx = i * 256 + tid;
    int row = idx >> 4, c = idx & 15;
    float4 v = (row < NB) ? ((const float4*)kv)[idx] : make_float4(0.f, 0.f, 0.f, 0.f);
    int byte = (row << 7) + (c << 3);
    byte ^= ((row & 7) << 4);
    *(uint2*)(&Atile[byte]) = make_uint2(packbf2(v.x, v.y), packbf2(v.z, v.w));
  }
  if (!PREP && tid < 16) ((float4*)qx_s)[tid] = ((const float4*)(q_x + bt * 64))[tid];

  bf16x8 bk[4][2], bw[4][2];
  float wsv[4], qqv[4], qvv[4];
  if (PREP) {
    // all global reads issued upfront, fully coalesced (16B/lane)
    const bf16x8* wkp = (const bf16x8*)((const char*)ws_f + PACK_BYTE) + 0;
    const bf16x8* wvp = (const bf16x8*)((const char*)ws_f + PACK_BYTE) + (WVP_S / 8);
    #pragma unroll
    for (int nt = 0; nt < 4; ++nt) {
      #pragma unroll
      for (int kt = 0; kt < 2; ++kt) {
        bk[nt][kt] = wkp[((head * 4 + nt) * 2 + kt) * 64 + lane];
        bw[nt][kt] = wvp[((head * 4 + nt) * 2 + kt) * 64 + lane];
      }
      wsv[nt] = wsc[nt * 16 + l15];
      qqv[nt] = ws_f[QQ_OFF + bt * 256 + obase + nt * 16 + l15];
      qvv[nt] = ws_f[QV_OFF + bt * 256 + obase + nt * 16 + l15];
    }
  }
  __syncthreads();

  if (!PREP) {
    {
      const int o = tid;
      float qq = 0.f, qvx = bv[o];
      const float4* wqr = (const float4*)(Wq + o * 64);
      const float4* wvr = (const float4*)(Wv + o * 128 + 64);
      const float4* qx4 = (const float4*)qx_s;
      #pragma unroll
      for (int i = 0; i < 16; ++i) {
        float4 a = wqr[i], x = qx4[i], b = wvr[i];
        qq  = fmaf(a.x, x.x, fmaf(a.y, x.y, fmaf(a.z, x.z, fmaf(a.w, x.w, qq))));
        qvx = fmaf(b.x, x.x, fmaf(b.y, x.y, fmaf(b.z, x.z, fmaf(b.w, x.w, qvx))));
      }
      qqb_s[o] = qq + bias[o & 63];
      qv_s[o] = qvx;
    }
    __syncthreads();
    #pragma unroll
    for (int nt = 0; nt < 4; ++nt) {
      const int o = obase + nt * 16 + l15;
      const float* wk = Wk + o * 64 + g * 8;
      const float* wv2 = Wv + o * 128 + g * 8;
      #pragma unroll
      for (int kt = 0; kt < 2; ++kt) {
        float4 a = *(const float4*)(wk + kt * 32);
        float4 b = *(const float4*)(wk + kt * 32 + 4);
        bf16x8 f;
        f[0] = bfs(a.x); f[1] = bfs(a.y); f[2] = bfs(a.z); f[3] = bfs(a.w);
        f[4] = bfs(b.x); f[5] = bfs(b.y); f[6] = bfs(b.z); f[7] = bfs(b.w);
        bk[nt][kt] = f;
        a = *(const float4*)(wv2 + kt * 32);
        b = *(const float4*)(wv2 + kt * 32 + 4);
        f[0] = bfs(a.x); f[1] = bfs(a.y); f[2] = bfs(a.z); f[3] = bfs(a.w);
        f[4] = bfs(b.x); f[5] = bfs(b.y); f[6] = bfs(b.z); f[7] = bfs(b.w);
        bw[nt][kt] = f;
      }
      wsv[nt] = wsc[nt * 16 + l15];
      qqv[nt] = qqb_s[obase + nt * 16 + l15];
      qvv[nt] = qv_s[obase + nt * 16 + l15];
    }
  }

  // ---- Phase C: score GEMM + tanh-score (wave-private: wave = head) ----
  #pragma unroll
  for (int mt = 0; mt < 8; ++mt) {
    int row = mt * 16 + l15;
    int byte0 = (row << 7) + g * 16;
    int swz = (l15 & 7) << 4;
    bf16x8 a0 = *(const bf16x8*)(&Atile[(byte0) ^ swz]);
    bf16x8 a1 = *(const bf16x8*)(&Atile[(byte0 + 64) ^ swz]);
    f32x4 acc[4];
    #pragma unroll
    for (int nt = 0; nt < 4; ++nt) {
      acc[nt] = (f32x4){0.f, 0.f, 0.f, 0.f};
      acc[nt] = __builtin_amdgcn_mfma_f32_16x16x32_bf16(a0, bk[nt][0], acc[nt], 0, 0, 0);
      acc[nt] = __builtin_amdgcn_mfma_f32_16x16x32_bf16(a1, bk[nt][1], acc[nt], 0, 0, 0);
    }
    #pragma unroll
    for (int r = 0; r < 4; ++r) {
      float s = 0.f;
      #pragma unroll
      for (int nt = 0; nt < 4; ++nt) {
        float xg = acc[nt][r] + qqv[nt];
        float e = __expf(2.f * xg);                    // tanh(x) = 1 - 2/(e^(2x)+1)
        float th = 1.f - 2.f * __builtin_amdgcn_rcpf(e + 1.f);
        s = fmaf(wsv[nt], th, s);
      }
      s += __shfl_xor(s, 1);
      s += __shfl_xor(s, 2);
      s += __shfl_xor(s, 4);
      s += __shfl_xor(s, 8);
      if (l15 == 0) sc_s[mt * 16 + g * 4 + r][head] = s;
    }
  }

  // ---- Phase D: softmax over n=127 (wave-local; no barrier needed) ----
  float w1, w2;
  {
    float s1 = sc_s[lane][head];
    float s2 = (lane < 63) ? sc_s[64 + lane][head] : -1e30f;
    float m = fmaxf(s1, s2);
    #pragma unroll
    for (int d = 1; d < 64; d <<= 1) m = fmaxf(m, __shfl_xor(m, d));
    float e1 = __expf(s1 - m);
    float e2 = (lane < 63) ? __expf(s2 - m) : 0.f;
    float sum = e1 + e2;
    #pragma unroll
    for (int d = 1; d < 64; d <<= 1) sum += __shfl_xor(sum, d);
    float inv = __builtin_amdgcn_rcpf(sum);
    w1 = e1 * inv;        // weight for row lane
    w2 = e2 * inv;        // weight for row 64+lane (row 127 -> 0)
  }

  // ---- Phase E: value GEMM + weighted reduce ----
  float cs[4] = {0.f, 0.f, 0.f, 0.f};
  #pragma unroll
  for (int mt = 0; mt < 8; ++mt) {
    int row = mt * 16 + l15;
    int byte0 = (row << 7) + g * 16;
    int swz = (l15 & 7) << 4;
    bf16x8 a0 = *(const bf16x8*)(&Atile[(byte0) ^ swz]);
    bf16x8 a1 = *(const bf16x8*)(&Atile[(byte0 + 64) ^ swz]);
    f32x4 vac[4];
    #pragma unroll
    for (int nt = 0; nt < 4; ++nt) {
      vac[nt] = (f32x4){0.f, 0.f, 0.f, 0.f};
      vac[nt] = __builtin_amdgcn_mfma_f32_16x16x32_bf16(a0, bw[nt][0], vac[nt], 0, 0, 0);
      vac[nt] = __builtin_amdgcn_mfma_f32_16x16x32_bf16(a1, bw[nt][1], vac[nt], 0, 0, 0);
    }
    #pragma unroll
    for (int r = 0; r < 4; ++r) {
      float wgt = __shfl((mt < 4) ? w1 : w2, (mt & 3) * 16 + g * 4 + r);
      #pragma unroll
      for (int nt = 0; nt < 4; ++nt)
        cs[nt] = fmaf(vac[nt][r], wgt, cs[nt]);
    }
  }
  #pragma unroll
  for (int nt = 0; nt < 4; ++nt) {
    cs[nt] += __shfl_xor(cs[nt], 16);
    cs[nt] += __shfl_xor(cs[nt], 32);
  }
  if (g == 0) {
    #pragma unroll
    for (int nt = 0; nt < 4; ++nt)
      out[bt * 256 + obase + nt * 16 + l15] = cs[nt] + qvv[nt];
  }
}

extern "C" void kernel_launch(void* const* d_in, const int* in_sizes, int n_in,
                              void* d_out, int out_size, void* d_ws, size_t ws_size,
                              hipStream_t stream) {
  const float* q_x  = (const float*)d_in[0];
  const float* kv_x = (const float*)d_in[1];
  const float* Wk   = (const float*)d_in[2];
  const float* Wq   = (const float*)d_in[3];
  const float* Wv   = (const float*)d_in[4];
  const float* bv   = (const float*)d_in[5];
  const float* bias = (const float*)d_in[6];
  const float* wsc  = (const float*)d_in[7];
  // d_in[8] = bs: constant across neighbors -> cancels in softmax, unused.
  float* out = (float*)d_out;
  float* ws_f = (float*)d_ws;

  if (ws_size >= WS_NEEDED) {
    prep_kernel<<<48, 256, 0, stream>>>(q_x, Wq, Wv, Wk, bv, bias, ws_f);
    rnn_attn_kernel<1><<<1024, 256, 0, stream>>>(q_x, kv_x, Wk, Wq, Wv, bv, bias, wsc, ws_f, out);
  } else {
    rnn_attn_kernel<0><<<1024, 256, 0, stream>>>(q_x, kv_x, Wk, Wq, Wv, bv, bias, wsc, ws_f, out);
  }
}